// Round 1
// baseline (2330.275 us; speedup 1.0000x reference)
//
#include <hip/hip_runtime.h>
#include <hip/hip_bf16.h>
#include <math.h>

#define H_ 512
#define VN_ 1000
#define NG_ 10003   // VT+3
#define NGP_ 10048  // padded N for MFMA tiles
#define A_ 50
#define B_ 8
#define L_ 128
#define R_ 1024     // L*B

typedef __hip_bfloat16 bf16;
typedef __attribute__((ext_vector_type(8))) short bf16x8;
typedef __attribute__((ext_vector_type(4))) float f32x4;

__device__ __forceinline__ float sigf(float x) { return 1.0f / (1.0f + expf(-x)); }

// ---------------- init: zero hs, barrier counter, loss accumulator ----------------
__global__ void k_init(float* hs, int* bar, float* out)
{
    size_t i = (size_t)blockIdx.x * blockDim.x + threadIdx.x;
    size_t n = (size_t)L_ * B_ * H_;
    for (size_t k = i; k < n; k += (size_t)gridDim.x * blockDim.x) hs[k] = 0.f;
    if (i == 0) { bar[0] = 0; out[0] = 0.f; }
}

// ---------------- W_g (f32 [1536][10003]) -> bf16 padded [1536][10048] ----------------
__global__ void k_wgconv(const float* __restrict__ Wg, bf16* __restrict__ Wgb)
{
    size_t total = (size_t)1536 * NGP_;
    for (size_t i = (size_t)blockIdx.x * blockDim.x + threadIdx.x; i < total;
         i += (size_t)gridDim.x * blockDim.x) {
        size_t k = i / NGP_, n = i - k * NGP_;
        float v = (n < NG_) ? Wg[k * NG_ + n] : 0.f;
        Wgb[i] = __float2bfloat16(v);
    }
}

// ---------------- embedding concat: X[r=t*8+b][512] = [embN[n_in], embT[t_in]] ----------------
__global__ void k_embed(const int* __restrict__ nt, const int* __restrict__ tt,
                        const float* __restrict__ embN, const float* __restrict__ embT,
                        float* __restrict__ X)
{
    int i = blockIdx.x * blockDim.x + threadIdx.x;   // < 1024*512
    int r = i >> 9, k = i & 511;
    int t = r >> 3, b = r & 7;
    float v;
    if (k < 256) {
        int id = (t == 0) ? 0 : nt[b * L_ + t - 1];
        v = embN[id * 256 + k];
    } else {
        int id = (t == 0) ? 0 : tt[b * L_ + t - 1];
        v = embT[id * 256 + (k - 256)];
    }
    X[i] = v;
}

// ---------------- generic fp32 GEMM: C[M][N] = A[M][K] * W[N][K]^T (+b1)(+b2) ----------------
__launch_bounds__(256)
__global__ void k_gemm_at(const float* __restrict__ A, const float* __restrict__ W,
                          const float* __restrict__ b1, const float* __restrict__ b2,
                          float* __restrict__ C, int N, int K)
{
    __shared__ float As[64][17];
    __shared__ float Wt[64][17];
    const int m0 = blockIdx.y * 64;
    const int n0 = blockIdx.x * 64;
    const int tid = threadIdx.x;
    const int ty = tid >> 4, tx = tid & 15;
    float acc[4][4] = {};
    for (int k0 = 0; k0 < K; k0 += 16) {
        __syncthreads();
        for (int i = tid; i < 64 * 16; i += 256) {
            int r = i >> 4, c = i & 15;
            As[r][c] = A[(size_t)(m0 + r) * K + k0 + c];
            Wt[r][c] = W[(size_t)(n0 + r) * K + k0 + c];
        }
        __syncthreads();
        #pragma unroll
        for (int kk = 0; kk < 16; ++kk) {
            float av[4], wv[4];
            #pragma unroll
            for (int i2 = 0; i2 < 4; ++i2) av[i2] = As[ty * 4 + i2][kk];
            #pragma unroll
            for (int j2 = 0; j2 < 4; ++j2) wv[j2] = Wt[tx * 4 + j2][kk];
            #pragma unroll
            for (int i2 = 0; i2 < 4; ++i2)
                #pragma unroll
                for (int j2 = 0; j2 < 4; ++j2)
                    acc[i2][j2] += av[i2] * wv[j2];
        }
    }
    #pragma unroll
    for (int i2 = 0; i2 < 4; ++i2) {
        int m = m0 + ty * 4 + i2;
        #pragma unroll
        for (int j2 = 0; j2 < 4; ++j2) {
            int n = n0 + tx * 4 + j2;
            float v = acc[i2][j2];
            if (b1) v += b1[n];
            if (b2) v += b2[n];
            C[(size_t)m * N + n] = v;
        }
    }
}

// ---------------- persistent sequential LSTM, 32 blocks, 1 grid-barrier per step ----------------
#define LSTM_BLOCKS 32
__launch_bounds__(256, 1)
__global__ void k_lstm(const float* __restrict__ Whh, const float* __restrict__ xg,
                       float* __restrict__ hs, int* __restrict__ bar)
{
    __shared__ __align__(16) float hbuf[B_][516];   // padded stride: bank spread for float4
    __shared__ float gl[4][16][9];
    __shared__ float cbuf[16][B_];
    const int tid = threadIdx.x;
    const int u_l = tid >> 4;          // 0..15  local hidden unit
    const int gp  = (tid >> 3) & 1;    // gate pair: {i,f} or {g,o}
    const int b   = tid & 7;
    const int U0  = blockIdx.x * 16;   // block owns units U0..U0+15
    const int j0 = (2 * gp) * 512 + U0 + u_l;
    const int j1 = (2 * gp + 1) * 512 + U0 + u_l;
    const float4* __restrict__ w0 = (const float4*)(Whh + (size_t)j0 * 512);
    const float4* __restrict__ w1 = (const float4*)(Whh + (size_t)j1 * 512);

    for (int i = tid; i < B_ * 516; i += 256) ((float*)hbuf)[i] = 0.f;
    if (tid < 128) cbuf[tid >> 3][tid & 7] = 0.f;
    __syncthreads();

    for (int t = 0; t < L_; ++t) {
        float acc0 = xg[((size_t)t * B_ + b) * 2048 + j0];
        float acc1 = xg[((size_t)t * B_ + b) * 2048 + j1];
        const float4* hb = (const float4*)hbuf[b];
        #pragma unroll 8
        for (int kk = 0; kk < 128; ++kk) {
            float4 hv = hb[kk];
            float4 a = w0[kk];
            float4 c = w1[kk];
            acc0 += a.x * hv.x + a.y * hv.y + a.z * hv.z + a.w * hv.w;
            acc1 += c.x * hv.x + c.y * hv.y + c.z * hv.z + c.w * hv.w;
        }
        gl[2 * gp][u_l][b] = acc0;
        gl[2 * gp + 1][u_l][b] = acc1;
        __syncthreads();
        if (tid < 128) {   // pointwise LSTM cell for (u, b)
            int u = tid >> 3, bb = tid & 7;
            float iv = sigf(gl[0][u][bb]);
            float fv = sigf(gl[1][u][bb]);
            float gv = tanhf(gl[2][u][bb]);
            float ov = sigf(gl[3][u][bb]);
            float c  = fv * cbuf[u][bb] + iv * gv;
            cbuf[u][bb] = c;
            hs[((size_t)t * B_ + bb) * H_ + U0 + u] = ov * tanhf(c);
        }
        __syncthreads();
        if (tid == 0) {   // device-scope grid barrier (monotonic counter)
            __threadfence();
            __hip_atomic_fetch_add(bar, 1, __ATOMIC_ACQ_REL, __HIP_MEMORY_SCOPE_AGENT);
            const int target = LSTM_BLOCKS * (t + 1);
            while (__hip_atomic_load(bar, __ATOMIC_ACQUIRE, __HIP_MEMORY_SCOPE_AGENT) < target)
                __builtin_amdgcn_s_sleep(2);
        }
        __syncthreads();
        const float* hsrc = hs + (size_t)t * B_ * H_;   // reload full h_t
        for (int i = tid; i < B_ * H_; i += 256)
            hbuf[i >> 9][i & 511] = hsrc[i];
        __syncthreads();
    }
}

// ---------------- attention + context + gcat(bf16) + st, one block per (t,b) ----------------
__launch_bounds__(256)
__global__ void k_attn(const float* __restrict__ hs, const float* __restrict__ km,
                       const float* __restrict__ q, const float* __restrict__ vw,
                       const float* __restrict__ vb, const int* __restrict__ nt,
                       const int* __restrict__ pt, const float* __restrict__ Wsv,
                       const float* __restrict__ bs, bf16* __restrict__ gcat,
                       float* __restrict__ logattn, float* __restrict__ stbuf)
{
    const int r = blockIdx.x;
    const int t = r >> 3, b = r & 7;
    const int tid = threadIdx.x;
    const int lane = tid & 63, wave = tid >> 6;
    int s = t - A_; if (s < 0) s = 0;
    __shared__ float qv[512];
    __shared__ float vwl[512];
    __shared__ float sc[A_];
    __shared__ float attn[A_];
    __shared__ float red[4];
    for (int i = tid; i < 512; i += 256) { qv[i] = q[(size_t)r * 512 + i]; vwl[i] = vw[i]; }
    __syncthreads();
    for (int a = wave; a < A_; a += 4) {
        int pos = s + a;
        float v = -1e20f;
        bool masked = (pos >= t) || (nt[b * L_ + pos] == VN_ - 1);
        if (!masked) {
            const float* kr = km + (size_t)(pos * B_ + b) * 512;
            float p = 0.f;
            for (int k = lane; k < 512; k += 64)
                p += vwl[k] * tanhf(qv[k] + kr[k]);
            for (int off = 32; off; off >>= 1) p += __shfl_down(p, off);
            v = p + vb[0];
        }
        if (lane == 0) sc[a] = v;
    }
    __syncthreads();
    if (tid < 64) {   // masked softmax over 50 (exact -1e20 semantics; all-masked -> uniform)
        float v = (tid < A_) ? sc[tid] : -INFINITY;
        float m = v;
        for (int off = 32; off; off >>= 1) m = fmaxf(m, __shfl_xor(m, off));
        float e = (tid < A_) ? expf(v - m) : 0.f;
        float d = e;
        for (int off = 32; off; off >>= 1) d += __shfl_xor(d, off);
        if (tid < A_) {
            attn[tid] = e / d;
            logattn[(size_t)r * A_ + tid] = (v - m) - logf(d);
        }
    }
    __syncthreads();
    const int k0 = tid * 2;
    float c0 = 0.f, c1 = 0.f;
    for (int a = 0; a < A_; ++a) {
        int pos = s + a;
        if (pos >= t) break;   // hs rows >= t were zeros at step t (ref semantics)
        float w = attn[a];
        const float2 hv = *(const float2*)(hs + (size_t)(pos * B_ + b) * 512 + k0);
        c0 += w * hv.x; c1 += w * hv.y;
    }
    const float2 hcur = *(const float2*)(hs + (size_t)(t * B_ + b) * 512 + k0);
    int par = (t == 0) ? 0 : pt[b * L_ + t - 1];
    float2 hpar = make_float2(0.f, 0.f);
    if (par < t) hpar = *(const float2*)(hs + (size_t)(par * B_ + b) * 512 + k0);
    bf16* g = gcat + (size_t)r * 1536;
    g[k0]            = __float2bfloat16(c0);
    g[k0 + 1]        = __float2bfloat16(c1);
    g[512 + k0]      = __float2bfloat16(hcur.x);
    g[512 + k0 + 1]  = __float2bfloat16(hcur.y);
    g[1024 + k0]     = __float2bfloat16(hpar.x);
    g[1024 + k0 + 1] = __float2bfloat16(hpar.y);
    float part = c0 * Wsv[k0] + c1 * Wsv[k0 + 1]
               + hcur.x * Wsv[512 + k0] + hcur.y * Wsv[512 + k0 + 1];
    for (int off = 32; off; off >>= 1) part += __shfl_down(part, off);
    if (lane == 0) red[wave] = part;
    __syncthreads();
    if (tid == 0) {
        float z = red[0] + red[1] + red[2] + red[3] + bs[0];
        stbuf[r] = -log1pf(expf(-z));   // log_sigmoid(z)
    }
}

// ---------------- bf16 MFMA GEMM: LOG[1024][10048] = GC[1024][1536] x WGB[1536][10048] ----------------
__launch_bounds__(256)
__global__ void k_mfma(const bf16* __restrict__ Ag, const bf16* __restrict__ Bg,
                       float* __restrict__ C)
{
    __shared__ short Al[64][40];   // [m][k] 32k + pad
    __shared__ short Bl[64][40];   // [n][k] transposed, + pad
    const int m0 = blockIdx.y * 64, n0 = blockIdx.x * 64;
    const int tid = threadIdx.x;
    const int lane = tid & 63, wave = tid >> 6;
    f32x4 acc[4] = {};
    for (int k0 = 0; k0 < 1536; k0 += 32) {
        __syncthreads();
        {
            int r = tid >> 2, c = (tid & 3) * 8;
            bf16x8 v = *(const bf16x8*)(Ag + (size_t)(m0 + r) * 1536 + k0 + c);
            *(bf16x8*)&Al[r][c] = v;
        }
        {
            int kr = tid >> 3, cn = (tid & 7) * 8;
            bf16x8 v = *(const bf16x8*)(Bg + (size_t)(k0 + kr) * NGP_ + n0 + cn);
            #pragma unroll
            for (int e = 0; e < 8; ++e) Bl[cn + e][kr] = v[e];
        }
        __syncthreads();
        const int row = lane & 15, kg = (lane >> 4) * 8;
        bf16x8 a = *(const bf16x8*)&Al[wave * 16 + row][kg];
        #pragma unroll
        for (int f = 0; f < 4; ++f) {
            bf16x8 bv = *(const bf16x8*)&Bl[f * 16 + row][kg];
            acc[f] = __builtin_amdgcn_mfma_f32_16x16x32_bf16(a, bv, acc[f], 0, 0, 0);
        }
    }
    const int col = lane & 15, rq = (lane >> 4) * 4;
    #pragma unroll
    for (int f = 0; f < 4; ++f)
        #pragma unroll
        for (int i = 0; i < 4; ++i)
            C[(size_t)(m0 + wave * 16 + rq + i) * NGP_ + n0 + f * 16 + col] = acc[f][i];
}

// ---------------- per-row logsumexp / loss / argmax-pred ----------------
__launch_bounds__(256)
__global__ void k_loss(const float* __restrict__ logits, const float* __restrict__ bg,
                       const float* __restrict__ logattn, const float* __restrict__ stbuf,
                       const int* __restrict__ tt, float* __restrict__ out)
{
    const int r = blockIdx.x;
    const int t = r >> 3, b = r & 7;
    const int tid = threadIdx.x;
    const int lane = tid & 63, wave = tid >> 6;
    const float* row = logits + (size_t)r * NGP_;
    float vmax = -INFINITY; int vidx = 0;
    for (int n = tid; n < NG_; n += 256) {
        float v = row[n] + bg[n];
        if (v > vmax) { vmax = v; vidx = n; }   // strict > keeps first index per thread
    }
    __shared__ float smax[4]; __shared__ int sidx[4]; __shared__ float ssum[4];
    for (int off = 32; off; off >>= 1) {
        float om = __shfl_down(vmax, off); int oi = __shfl_down(vidx, off);
        if (om > vmax || (om == vmax && oi < vidx)) { vmax = om; vidx = oi; }
    }
    if (lane == 0) { smax[wave] = vmax; sidx[wave] = vidx; }
    __syncthreads();
    if (tid == 0) {
        for (int w = 1; w < 4; ++w)
            if (smax[w] > vmax || (smax[w] == vmax && sidx[w] < vidx)) { vmax = smax[w]; vidx = sidx[w]; }
        smax[0] = vmax; sidx[0] = vidx;
    }
    __syncthreads();
    vmax = smax[0];
    const int amax1 = sidx[0];
    float se = 0.f;
    for (int n = tid; n < NG_; n += 256) se += expf(row[n] + bg[n] - vmax);
    for (int off = 32; off; off >>= 1) se += __shfl_down(se, off);
    if (lane == 0) ssum[wave] = se;
    __syncthreads();
    if (tid == 0) {
        float d = ssum[0] + ssum[1] + ssum[2] + ssum[3];
        float lse = vmax + logf(d);
        float st = stbuf[r];
        const float* la = logattn + (size_t)r * A_;
        float lamax = la[0]; int aidx = 0;
        for (int a = 1; a < A_; ++a) if (la[a] > lamax) { lamax = la[a]; aidx = a; }
        float e1 = -expm1f(st);
        e1 = fminf(fmaxf(e1, 1e-18f), 1e18f);
        float lm = logf(e1);
        float p1 = st + vmax - lse;
        float p2 = lm + lamax;
        int pred = (p1 >= p2) ? amax1 : (NG_ + aidx);   // tie -> earlier (part1) index
        int tgt = tt[b * L_ + t];
        float loss = -(st + (row[tgt] + bg[tgt]) - lse);
        atomicAdd(&out[0], loss);
        out[1 + b * L_ + t] = (float)pred;
    }
}

extern "C" void kernel_launch(void* const* d_in, const int* in_sizes, int n_in,
                              void* d_out, int out_size, void* d_ws, size_t ws_size,
                              hipStream_t stream)
{
    (void)in_sizes; (void)n_in; (void)out_size; (void)ws_size;
    const int*   nt    = (const int*)d_in[0];
    const int*   tt    = (const int*)d_in[1];
    const int*   pt    = (const int*)d_in[2];
    const float* embN  = (const float*)d_in[3];
    const float* embT  = (const float*)d_in[4];
    const float* W_hid = (const float*)d_in[5];
    const float* b_hid = (const float*)d_in[6];
    const float* W_mem = (const float*)d_in[7];
    const float* b_mem = (const float*)d_in[8];
    const float* v_w   = (const float*)d_in[9];
    const float* v_b   = (const float*)d_in[10];
    const float* W_ih  = (const float*)d_in[11];
    const float* W_hh  = (const float*)d_in[12];
    const float* b_ih  = (const float*)d_in[13];
    const float* b_hh  = (const float*)d_in[14];
    const float* W_g   = (const float*)d_in[15];
    const float* b_g   = (const float*)d_in[16];
    const float* W_s   = (const float*)d_in[17];
    const float* b_s   = (const float*)d_in[18];
    float* out = (float*)d_out;

    char* ws = (char*)d_ws;
    size_t o = 0;
    bf16*  WGB = (bf16*)(ws + o);  o += (size_t)1536 * NGP_ * 2;   // 30.9 MB
    float* LOG = (float*)(ws + o); o += (size_t)R_ * NGP_ * 4;     // 41.2 MB
    float* XG  = (float*)(ws + o); o += (size_t)R_ * 2048 * 4;     // 8.4 MB
    float* HS  = (float*)(ws + o); o += (size_t)R_ * H_ * 4;       // 2 MB
    float* KM  = (float*)(ws + o); o += (size_t)R_ * H_ * 4;
    float* QB  = (float*)(ws + o); o += (size_t)R_ * H_ * 4;
    float* X   = (float*)(ws + o); o += (size_t)R_ * H_ * 4;
    bf16*  GC  = (bf16*)(ws + o);  o += (size_t)R_ * 1536 * 2;     // 3.1 MB
    float* LA  = (float*)(ws + o); o += (size_t)R_ * A_ * 4;
    float* ST  = (float*)(ws + o); o += (size_t)R_ * 4;
    int*   BAR = (int*)(ws + o);   o += 256;

    k_init<<<256, 256, 0, stream>>>(HS, BAR, out);
    k_wgconv<<<2048, 256, 0, stream>>>(W_g, WGB);
    k_embed<<<R_ * H_ / 256, 256, 0, stream>>>(nt, tt, embN, embT, X);
    k_gemm_at<<<dim3(2048 / 64, R_ / 64), 256, 0, stream>>>(X, W_ih, b_ih, b_hh, XG, 2048, 512);
    k_lstm<<<LSTM_BLOCKS, 256, 0, stream>>>(W_hh, XG, HS, BAR);
    k_gemm_at<<<dim3(512 / 64, R_ / 64), 256, 0, stream>>>(HS, W_mem, b_mem, nullptr, KM, 512, 512);
    k_gemm_at<<<dim3(512 / 64, R_ / 64), 256, 0, stream>>>(HS, W_hid, b_hid, nullptr, QB, 512, 512);
    k_attn<<<R_, 256, 0, stream>>>(HS, KM, QB, v_w, v_b, nt, pt, W_s, b_s, GC, LA, ST);
    k_mfma<<<dim3(NGP_ / 64, R_ / 64), 256, 0, stream>>>(GC, WGB, LOG);
    k_loss<<<R_, 256, 0, stream>>>(LOG, b_g, LA, ST, tt, out);
}

// Round 3
// 1245.469 us; speedup vs baseline: 1.8710x; 1.8710x over previous
//
#include <hip/hip_runtime.h>
#include <hip/hip_bf16.h>
#include <math.h>

#define H_ 512
#define VN_ 1000
#define NG_ 10003   // VT+3
#define NGP_ 10048  // padded N for MFMA tiles
#define A_ 50
#define B_ 8
#define L_ 128
#define R_ 1024     // L*B

typedef __hip_bfloat16 bf16;
typedef __attribute__((ext_vector_type(8))) short bf16x8;
typedef __attribute__((ext_vector_type(4))) float f32x4;

__device__ __forceinline__ float sigf(float x) { return 1.0f / (1.0f + expf(-x)); }

__device__ __forceinline__ short b16(float v) {
    __hip_bfloat16 h = __float2bfloat16(v);
    return *(short*)&h;
}

// ---------------- init: flags + loss accumulator ----------------
__global__ void k_init(int* flags, float* out)
{
    if (threadIdx.x < 32) flags[threadIdx.x] = 0;
    if (threadIdx.x == 0) out[0] = 0.f;
}

// ---------------- W_g (f32 [1536][10003]) -> bf16 padded [1536][10048] ----------------
__global__ void k_wgconv(const float* __restrict__ Wg, bf16* __restrict__ Wgb)
{
    size_t total = (size_t)1536 * NGP_;
    for (size_t i = (size_t)blockIdx.x * blockDim.x + threadIdx.x; i < total;
         i += (size_t)gridDim.x * blockDim.x) {
        size_t k = i / NGP_, n = i - k * NGP_;
        float v = (n < NG_) ? Wg[k * NG_ + n] : 0.f;
        Wgb[i] = __float2bfloat16(v);
    }
}

// ---------------- embedding concat: X[r=t*8+b][512] = [embN[n_in], embT[t_in]] ----------------
__global__ void k_embed(const int* __restrict__ nt, const int* __restrict__ tt,
                        const float* __restrict__ embN, const float* __restrict__ embT,
                        float* __restrict__ X)
{
    int i = blockIdx.x * blockDim.x + threadIdx.x;   // < 1024*512
    int r = i >> 9, k = i & 511;
    int t = r >> 3, b = r & 7;
    float v;
    if (k < 256) {
        int id = (t == 0) ? 0 : nt[b * L_ + t - 1];
        v = embN[id * 256 + k];
    } else {
        int id = (t == 0) ? 0 : tt[b * L_ + t - 1];
        v = embT[id * 256 + (k - 256)];
    }
    X[i] = v;
}

// ---------------- generic fp32 GEMM: C[M][N] = A[M][K] * W[N][K]^T (+b1)(+b2) ----------------
__launch_bounds__(256)
__global__ void k_gemm_at(const float* __restrict__ A, const float* __restrict__ W,
                          const float* __restrict__ b1, const float* __restrict__ b2,
                          float* __restrict__ C, int N, int K)
{
    __shared__ float As[64][17];
    __shared__ float Wt[64][17];
    const int m0 = blockIdx.y * 64;
    const int n0 = blockIdx.x * 64;
    const int tid = threadIdx.x;
    const int ty = tid >> 4, tx = tid & 15;
    float acc[4][4] = {};
    for (int k0 = 0; k0 < K; k0 += 16) {
        __syncthreads();
        for (int i = tid; i < 64 * 16; i += 256) {
            int r = i >> 4, c = i & 15;
            As[r][c] = A[(size_t)(m0 + r) * K + k0 + c];
            Wt[r][c] = W[(size_t)(n0 + r) * K + k0 + c];
        }
        __syncthreads();
        #pragma unroll
        for (int kk = 0; kk < 16; ++kk) {
            float av[4], wv[4];
            #pragma unroll
            for (int i2 = 0; i2 < 4; ++i2) av[i2] = As[ty * 4 + i2][kk];
            #pragma unroll
            for (int j2 = 0; j2 < 4; ++j2) wv[j2] = Wt[tx * 4 + j2][kk];
            #pragma unroll
            for (int i2 = 0; i2 < 4; ++i2)
                #pragma unroll
                for (int j2 = 0; j2 < 4; ++j2)
                    acc[i2][j2] += av[i2] * wv[j2];
        }
    }
    #pragma unroll
    for (int i2 = 0; i2 < 4; ++i2) {
        int m = m0 + ty * 4 + i2;
        #pragma unroll
        for (int j2 = 0; j2 < 4; ++j2) {
            int n = n0 + tx * 4 + j2;
            float v = acc[i2][j2];
            if (b1) v += b1[n];
            if (b2) v += b2[n];
            C[(size_t)m * N + n] = v;
        }
    }
}

// ---------------- persistent sequential LSTM ----------------
// 16 blocks; block x owns hidden units [x*32, x*32+32). Wave w computes gate w
// for those 32 units via MFMA with Whh fragments RESIDENT IN VGPRS (bf16).
// h exchanged between blocks as bf16 MFMA B-fragments in global memory
// (double-buffered by step parity); per-block flags + release/acquire fences.
#define LSTM_BLOCKS 16
__launch_bounds__(256, 1)
__global__ void k_lstm(const float* __restrict__ Whh, const float* __restrict__ xg,
                       float* __restrict__ hs, bf16* __restrict__ bfrag,
                       int* __restrict__ flags)
{
    __shared__ float gl[4][32][9];   // [gate][unit][batch] (+pad)
    const int tid  = threadIdx.x;
    const int lane = tid & 63;
    const int w    = tid >> 6;       // wave = gate index 0..3 (i,f,g,o)
    const int x    = blockIdx.x;
    const int m_l  = lane & 15;      // MFMA row within tile
    const int kg   = lane >> 4;      // k-group (8 elems)
    const int n    = lane & 15;      // MFMA col = batch (valid < 8)

    // ---- load this wave's Whh rows into VGPR bf16 A-fragments (once) ----
    // tile tau covers units [x*32 + tau*16, +16); rows = w*512 + unit.
    bf16x8 Wf0[16], Wf1[16];
    {
        const float* wr0 = Whh + (size_t)(w * 512 + x * 32 + m_l) * 512 + kg * 8;
        const float* wr1 = wr0 + (size_t)16 * 512;
        #pragma unroll
        for (int kt = 0; kt < 16; ++kt) {
            float4 a0 = *(const float4*)(wr0 + kt * 32);
            float4 a1 = *(const float4*)(wr0 + kt * 32 + 4);
            float4 c0 = *(const float4*)(wr1 + kt * 32);
            float4 c1 = *(const float4*)(wr1 + kt * 32 + 4);
            bf16x8 f0, f1;
            f0[0] = b16(a0.x); f0[1] = b16(a0.y); f0[2] = b16(a0.z); f0[3] = b16(a0.w);
            f0[4] = b16(a1.x); f0[5] = b16(a1.y); f0[6] = b16(a1.z); f0[7] = b16(a1.w);
            f1[0] = b16(c0.x); f1[1] = b16(c0.y); f1[2] = b16(c0.z); f1[3] = b16(c0.w);
            f1[4] = b16(c1.x); f1[5] = b16(c1.y); f1[6] = b16(c1.z); f1[7] = b16(c1.w);
            Wf0[kt] = f0; Wf1[kt] = f1;
        }
    }

    const int u_l = tid >> 3;        // pointwise: unit 0..31
    const int b   = tid & 7;         //            batch 0..7
    float creg = 0.f;                // cell state lives in a register

    for (int t = 0; t < L_; ++t) {
        // prefetch xg for this step (independent of h)
        const float* xr = xg + ((size_t)t * B_ + b) * 2048 + x * 32 + u_l;
        float xi = xr[0], xf = xr[512], xgg = xr[1024], xo = xr[1536];

        f32x4 acc0 = {0.f, 0.f, 0.f, 0.f};
        f32x4 acc1 = {0.f, 0.f, 0.f, 0.f};
        if (t > 0) {
            if (w == 0) {            // wait for all blocks to finish step t-1
                for (;;) {
                    int v = (lane < LSTM_BLOCKS)
                        ? __hip_atomic_load(&flags[lane], __ATOMIC_RELAXED, __HIP_MEMORY_SCOPE_AGENT)
                        : t;
                    if (__all(v >= t)) break;
                    __builtin_amdgcn_s_sleep(1);
                }
                __builtin_amdgcn_fence(__ATOMIC_ACQUIRE, "agent");
            }
            __syncthreads();
            // B-fragments of h_{t-1}: parity (t-1)&1 == (t+1)&1
            const bf16x8* bb = ((const bf16x8*)bfrag) + (size_t)((t + 1) & 1) * 1024 + lane;
            #pragma unroll
            for (int kt = 0; kt < 16; ++kt) {
                bf16x8 bv = bb[kt * 64];
                acc0 = __builtin_amdgcn_mfma_f32_16x16x32_bf16(Wf0[kt], bv, acc0, 0, 0, 0);
                acc1 = __builtin_amdgcn_mfma_f32_16x16x32_bf16(Wf1[kt], bv, acc1, 0, 0, 0);
            }
        } else {
            __syncthreads();
        }
        // D layout: col = lane&15 (batch), row = kg*4 + i (unit within tile)
        if (n < 8) {
            #pragma unroll
            for (int i = 0; i < 4; ++i) {
                gl[w][kg * 4 + i][n]      = acc0[i];
                gl[w][16 + kg * 4 + i][n] = acc1[i];
            }
        }
        __syncthreads();
        // pointwise LSTM cell: thread = (unit u_l, batch b)
        {
            float gi = gl[0][u_l][b] + xi;
            float gf = gl[1][u_l][b] + xf;
            float gg = gl[2][u_l][b] + xgg;
            float go = gl[3][u_l][b] + xo;
            float iv = sigf(gi), fv = sigf(gf), gv = tanhf(gg), ov = sigf(go);
            creg = fv * creg + iv * gv;
            float h = ov * tanhf(creg);
            hs[((size_t)t * B_ + b) * H_ + x * 32 + u_l] = h;
            // write h into its B-fragment slot: k-tile == x for this block
            int q = u_l >> 3, j = u_l & 7;
            bfrag[((size_t)(t & 1) * 16 + x) * 512 + (b + 16 * q) * 8 + j] = __float2bfloat16(h);
        }
        __syncthreads();             // all stores issued (compiler drains vmcnt)
        if (tid == 0) {
            __builtin_amdgcn_fence(__ATOMIC_RELEASE, "agent");
            __hip_atomic_store(&flags[x], t + 1, __ATOMIC_RELAXED, __HIP_MEMORY_SCOPE_AGENT);
        }
    }
}

// ---------------- attention + context + gcat(bf16) + st, one block per (t,b) ----------------
__launch_bounds__(256)
__global__ void k_attn(const float* __restrict__ hs, const float* __restrict__ km,
                       const float* __restrict__ q, const float* __restrict__ vw,
                       const float* __restrict__ vb, const int* __restrict__ nt,
                       const int* __restrict__ pt, const float* __restrict__ Wsv,
                       const float* __restrict__ bs, bf16* __restrict__ gcat,
                       float* __restrict__ logattn, float* __restrict__ stbuf)
{
    const int r = blockIdx.x;
    const int t = r >> 3, b = r & 7;
    const int tid = threadIdx.x;
    const int lane = tid & 63, wave = tid >> 6;
    int s = t - A_; if (s < 0) s = 0;
    __shared__ float qv[512];
    __shared__ float vwl[512];
    __shared__ float sc[A_];
    __shared__ float attn[A_];
    __shared__ float red[4];
    for (int i = tid; i < 512; i += 256) { qv[i] = q[(size_t)r * 512 + i]; vwl[i] = vw[i]; }
    __syncthreads();
    for (int a = wave; a < A_; a += 4) {
        int pos = s + a;
        float v = -1e20f;
        bool masked = (pos >= t) || (nt[b * L_ + pos] == VN_ - 1);
        if (!masked) {
            const float* kr = km + (size_t)(pos * B_ + b) * 512;
            float p = 0.f;
            for (int k = lane; k < 512; k += 64)
                p += vwl[k] * tanhf(qv[k] + kr[k]);
            for (int off = 32; off; off >>= 1) p += __shfl_down(p, off);
            v = p + vb[0];
        }
        if (lane == 0) sc[a] = v;
    }
    __syncthreads();
    if (tid < 64) {   // masked softmax over 50 (exact -1e20 semantics; all-masked -> uniform)
        float v = (tid < A_) ? sc[tid] : -INFINITY;
        float m = v;
        for (int off = 32; off; off >>= 1) m = fmaxf(m, __shfl_xor(m, off));
        float e = (tid < A_) ? expf(v - m) : 0.f;
        float d = e;
        for (int off = 32; off; off >>= 1) d += __shfl_xor(d, off);
        if (tid < A_) {
            attn[tid] = e / d;
            logattn[(size_t)r * A_ + tid] = (v - m) - logf(d);
        }
    }
    __syncthreads();
    const int k0 = tid * 2;
    float c0 = 0.f, c1 = 0.f;
    for (int a = 0; a < A_; ++a) {
        int pos = s + a;
        if (pos >= t) break;   // hs rows >= t were zeros at step t (ref semantics)
        float w = attn[a];
        const float2 hv = *(const float2*)(hs + (size_t)(pos * B_ + b) * 512 + k0);
        c0 += w * hv.x; c1 += w * hv.y;
    }
    const float2 hcur = *(const float2*)(hs + (size_t)(t * B_ + b) * 512 + k0);
    int par = (t == 0) ? 0 : pt[b * L_ + t - 1];
    float2 hpar = make_float2(0.f, 0.f);
    if (par < t) hpar = *(const float2*)(hs + (size_t)(par * B_ + b) * 512 + k0);
    bf16* g = gcat + (size_t)r * 1536;
    g[k0]            = __float2bfloat16(c0);
    g[k0 + 1]        = __float2bfloat16(c1);
    g[512 + k0]      = __float2bfloat16(hcur.x);
    g[512 + k0 + 1]  = __float2bfloat16(hcur.y);
    g[1024 + k0]     = __float2bfloat16(hpar.x);
    g[1024 + k0 + 1] = __float2bfloat16(hpar.y);
    float part = c0 * Wsv[k0] + c1 * Wsv[k0 + 1]
               + hcur.x * Wsv[512 + k0] + hcur.y * Wsv[512 + k0 + 1];
    for (int off = 32; off; off >>= 1) part += __shfl_down(part, off);
    if (lane == 0) red[wave] = part;
    __syncthreads();
    if (tid == 0) {
        float z = red[0] + red[1] + red[2] + red[3] + bs[0];
        stbuf[r] = -log1pf(expf(-z));   // log_sigmoid(z)
    }
}

// ---------------- bf16 MFMA GEMM: LOG[1024][10048] = GC[1024][1536] x WGB[1536][10048] ----------------
__launch_bounds__(256)
__global__ void k_mfma(const bf16* __restrict__ Ag, const bf16* __restrict__ Bg,
                       float* __restrict__ C)
{
    __shared__ short Al[64][40];   // [m][k] 32k + pad
    __shared__ short Bl[64][40];   // [n][k] transposed, + pad
    const int m0 = blockIdx.y * 64, n0 = blockIdx.x * 64;
    const int tid = threadIdx.x;
    const int lane = tid & 63, wave = tid >> 6;
    f32x4 acc[4] = {};
    for (int k0 = 0; k0 < 1536; k0 += 32) {
        __syncthreads();
        {
            int r = tid >> 2, c = (tid & 3) * 8;
            bf16x8 v = *(const bf16x8*)(Ag + (size_t)(m0 + r) * 1536 + k0 + c);
            *(bf16x8*)&Al[r][c] = v;
        }
        {
            int kr = tid >> 3, cn = (tid & 7) * 8;
            bf16x8 v = *(const bf16x8*)(Bg + (size_t)(k0 + kr) * NGP_ + n0 + cn);
            #pragma unroll
            for (int e = 0; e < 8; ++e) Bl[cn + e][kr] = v[e];
        }
        __syncthreads();
        const int row = lane & 15, kg = (lane >> 4) * 8;
        bf16x8 a = *(const bf16x8*)&Al[wave * 16 + row][kg];
        #pragma unroll
        for (int f = 0; f < 4; ++f) {
            bf16x8 bv = *(const bf16x8*)&Bl[f * 16 + row][kg];
            acc[f] = __builtin_amdgcn_mfma_f32_16x16x32_bf16(a, bv, acc[f], 0, 0, 0);
        }
    }
    const int col = lane & 15, rq = (lane >> 4) * 4;
    #pragma unroll
    for (int f = 0; f < 4; ++f)
        #pragma unroll
        for (int i = 0; i < 4; ++i)
            C[(size_t)(m0 + wave * 16 + rq + i) * NGP_ + n0 + f * 16 + col] = acc[f][i];
}

// ---------------- per-row logsumexp / loss / argmax-pred ----------------
__launch_bounds__(256)
__global__ void k_loss(const float* __restrict__ logits, const float* __restrict__ bg,
                       const float* __restrict__ logattn, const float* __restrict__ stbuf,
                       const int* __restrict__ tt, float* __restrict__ out)
{
    const int r = blockIdx.x;
    const int t = r >> 3, b = r & 7;
    const int tid = threadIdx.x;
    const int lane = tid & 63, wave = tid >> 6;
    const float* row = logits + (size_t)r * NGP_;
    float vmax = -INFINITY; int vidx = 0;
    for (int n = tid; n < NG_; n += 256) {
        float v = row[n] + bg[n];
        if (v > vmax) { vmax = v; vidx = n; }   // strict > keeps first index per thread
    }
    __shared__ float smax[4]; __shared__ int sidx[4]; __shared__ float ssum[4];
    for (int off = 32; off; off >>= 1) {
        float om = __shfl_down(vmax, off); int oi = __shfl_down(vidx, off);
        if (om > vmax || (om == vmax && oi < vidx)) { vmax = om; vidx = oi; }
    }
    if (lane == 0) { smax[wave] = vmax; sidx[wave] = vidx; }
    __syncthreads();
    if (tid == 0) {
        for (int w = 1; w < 4; ++w)
            if (smax[w] > vmax || (smax[w] == vmax && sidx[w] < vidx)) { vmax = smax[w]; vidx = sidx[w]; }
        smax[0] = vmax; sidx[0] = vidx;
    }
    __syncthreads();
    vmax = smax[0];
    const int amax1 = sidx[0];
    float se = 0.f;
    for (int n = tid; n < NG_; n += 256) se += expf(row[n] + bg[n] - vmax);
    for (int off = 32; off; off >>= 1) se += __shfl_down(se, off);
    if (lane == 0) ssum[wave] = se;
    __syncthreads();
    if (tid == 0) {
        float d = ssum[0] + ssum[1] + ssum[2] + ssum[3];
        float lse = vmax + logf(d);
        float st = stbuf[r];
        const float* la = logattn + (size_t)r * A_;
        float lamax = la[0]; int aidx = 0;
        for (int a = 1; a < A_; ++a) if (la[a] > lamax) { lamax = la[a]; aidx = a; }
        float e1 = -expm1f(st);
        e1 = fminf(fmaxf(e1, 1e-18f), 1e18f);
        float lm = logf(e1);
        float p1 = st + vmax - lse;
        float p2 = lm + lamax;
        int pred = (p1 >= p2) ? amax1 : (NG_ + aidx);   // tie -> earlier (part1) index
        int tgt = tt[b * L_ + t];
        float loss = -(st + (row[tgt] + bg[tgt]) - lse);
        atomicAdd(&out[0], loss);
        out[1 + b * L_ + t] = (float)pred;
    }
}

extern "C" void kernel_launch(void* const* d_in, const int* in_sizes, int n_in,
                              void* d_out, int out_size, void* d_ws, size_t ws_size,
                              hipStream_t stream)
{
    (void)in_sizes; (void)n_in; (void)out_size; (void)ws_size;
    const int*   nt    = (const int*)d_in[0];
    const int*   tt    = (const int*)d_in[1];
    const int*   pt    = (const int*)d_in[2];
    const float* embN  = (const float*)d_in[3];
    const float* embT  = (const float*)d_in[4];
    const float* W_hid = (const float*)d_in[5];
    const float* b_hid = (const float*)d_in[6];
    const float* W_mem = (const float*)d_in[7];
    const float* b_mem = (const float*)d_in[8];
    const float* v_w   = (const float*)d_in[9];
    const float* v_b   = (const float*)d_in[10];
    const float* W_ih  = (const float*)d_in[11];
    const float* W_hh  = (const float*)d_in[12];
    const float* b_ih  = (const float*)d_in[13];
    const float* b_hh  = (const float*)d_in[14];
    const float* W_g   = (const float*)d_in[15];
    const float* b_g   = (const float*)d_in[16];
    const float* W_s   = (const float*)d_in[17];
    const float* b_s   = (const float*)d_in[18];
    float* out = (float*)d_out;

    char* ws = (char*)d_ws;
    size_t o = 0;
    bf16*  WGB = (bf16*)(ws + o);  o += (size_t)1536 * NGP_ * 2;   // 30.9 MB
    float* LOG = (float*)(ws + o); o += (size_t)R_ * NGP_ * 4;     // 41.2 MB
    float* XG  = (float*)(ws + o); o += (size_t)R_ * 2048 * 4;     // 8.4 MB
    float* HS  = (float*)(ws + o); o += (size_t)R_ * H_ * 4;       // 2 MB
    float* KM  = (float*)(ws + o); o += (size_t)R_ * H_ * 4;
    float* QB  = (float*)(ws + o); o += (size_t)R_ * H_ * 4;
    float* X   = (float*)(ws + o); o += (size_t)R_ * H_ * 4;
    bf16*  GC  = (bf16*)(ws + o);  o += (size_t)R_ * 1536 * 2;     // 3.1 MB
    float* LA  = (float*)(ws + o); o += (size_t)R_ * A_ * 4;
    float* ST  = (float*)(ws + o); o += (size_t)R_ * 4;
    bf16*  BFR = (bf16*)(ws + o);  o += (size_t)2 * 16 * 512 * 2;  // h B-fragments, 2 parities
    int*   FLG = (int*)(ws + o);   o += 256;

    k_init<<<1, 256, 0, stream>>>(FLG, out);
    k_wgconv<<<2048, 256, 0, stream>>>(W_g, WGB);
    k_embed<<<R_ * H_ / 256, 256, 0, stream>>>(nt, tt, embN, embT, X);
    k_gemm_at<<<dim3(2048 / 64, R_ / 64), 256, 0, stream>>>(X, W_ih, b_ih, b_hh, XG, 2048, 512);
    k_lstm<<<LSTM_BLOCKS, 256, 0, stream>>>(W_hh, XG, HS, BFR, FLG);
    k_gemm_at<<<dim3(512 / 64, R_ / 64), 256, 0, stream>>>(HS, W_mem, b_mem, nullptr, KM, 512, 512);
    k_gemm_at<<<dim3(512 / 64, R_ / 64), 256, 0, stream>>>(HS, W_hid, b_hid, nullptr, QB, 512, 512);
    k_attn<<<R_, 256, 0, stream>>>(HS, KM, QB, v_w, v_b, nt, pt, W_s, b_s, GC, LA, ST);
    k_mfma<<<dim3(NGP_ / 64, R_ / 64), 256, 0, stream>>>(GC, WGB, LOG);
    k_loss<<<R_, 256, 0, stream>>>(LOG, b_g, LA, ST, tt, out);
}

// Round 4
// 968.166 us; speedup vs baseline: 2.4069x; 1.2864x over previous
//
#include <hip/hip_runtime.h>
#include <hip/hip_bf16.h>
#include <math.h>

#define H_ 512
#define VN_ 1000
#define NG_ 10003   // VT+3
#define NGP_ 10048  // padded N for MFMA tiles
#define A_ 50
#define B_ 8
#define L_ 128
#define R_ 1024     // L*B

typedef __hip_bfloat16 bf16;
typedef __attribute__((ext_vector_type(8))) short bf16x8;
typedef __attribute__((ext_vector_type(4))) float f32x4;

typedef union { unsigned long long u[2]; bf16x8 v; } frag_u;

__device__ __forceinline__ float sigf(float x) { return 1.0f / (1.0f + expf(-x)); }

__device__ __forceinline__ short b16(float v) {
    __hip_bfloat16 h = __float2bfloat16(v);
    return *(short*)&h;
}

__device__ __forceinline__ unsigned long long ald(const unsigned long long* p) {
    return __hip_atomic_load(p, __ATOMIC_RELAXED, __HIP_MEMORY_SCOPE_AGENT);
}
__device__ __forceinline__ void ast(unsigned long long* p, unsigned long long v) {
    __hip_atomic_store(p, v, __ATOMIC_RELAXED, __HIP_MEMORY_SCOPE_AGENT);
}

// ---------------- init: flags + loss accumulator ----------------
__global__ void k_init(int* flags, float* out)
{
    if (threadIdx.x < 32)
        __hip_atomic_store(&flags[threadIdx.x], 0, __ATOMIC_RELAXED, __HIP_MEMORY_SCOPE_AGENT);
    if (threadIdx.x == 0) out[0] = 0.f;
}

// ---------------- W_g (f32 [1536][10003]) -> bf16 padded [1536][10048] ----------------
__global__ void k_wgconv(const float* __restrict__ Wg, bf16* __restrict__ Wgb)
{
    size_t total = (size_t)1536 * NGP_;
    for (size_t i = (size_t)blockIdx.x * blockDim.x + threadIdx.x; i < total;
         i += (size_t)gridDim.x * blockDim.x) {
        size_t k = i / NGP_, n = i - k * NGP_;
        float v = (n < NG_) ? Wg[k * NG_ + n] : 0.f;
        Wgb[i] = __float2bfloat16(v);
    }
}

// ---------------- flat f32 -> bf16 convert (W_ih) ----------------
__global__ void k_w2b(const float* __restrict__ src, bf16* __restrict__ dst, int n)
{
    for (int i = blockIdx.x * blockDim.x + threadIdx.x; i < n; i += gridDim.x * blockDim.x)
        dst[i] = __float2bfloat16(src[i]);
}

// ---------------- embedding concat -> bf16: X[r=t*8+b][512] = [embN[n_in], embT[t_in]] ----------------
__global__ void k_embed(const int* __restrict__ nt, const int* __restrict__ tt,
                        const float* __restrict__ embN, const float* __restrict__ embT,
                        bf16* __restrict__ X)
{
    int i = blockIdx.x * blockDim.x + threadIdx.x;   // < 1024*512
    int r = i >> 9, k = i & 511;
    int t = r >> 3, b = r & 7;
    float v;
    if (k < 256) {
        int id = (t == 0) ? 0 : nt[b * L_ + t - 1];
        v = embN[id * 256 + k];
    } else {
        int id = (t == 0) ? 0 : tt[b * L_ + t - 1];
        v = embT[id * 256 + (k - 256)];
    }
    X[i] = __float2bfloat16(v);
}

// ---------------- generic fp32 GEMM: C[M][N] = A[M][K] * W[N][K]^T (+b1) ----------------
__launch_bounds__(256)
__global__ void k_gemm_at(const float* __restrict__ A, const float* __restrict__ W,
                          const float* __restrict__ b1,
                          float* __restrict__ C, int N, int K)
{
    __shared__ float As[64][17];
    __shared__ float Wt[64][17];
    const int m0 = blockIdx.y * 64;
    const int n0 = blockIdx.x * 64;
    const int tid = threadIdx.x;
    const int ty = tid >> 4, tx = tid & 15;
    float acc[4][4] = {};
    for (int k0 = 0; k0 < K; k0 += 16) {
        __syncthreads();
        for (int i = tid; i < 64 * 16; i += 256) {
            int r = i >> 4, c = i & 15;
            As[r][c] = A[(size_t)(m0 + r) * K + k0 + c];
            Wt[r][c] = W[(size_t)(n0 + r) * K + k0 + c];
        }
        __syncthreads();
        #pragma unroll
        for (int kk = 0; kk < 16; ++kk) {
            float av[4], wv[4];
            #pragma unroll
            for (int i2 = 0; i2 < 4; ++i2) av[i2] = As[ty * 4 + i2][kk];
            #pragma unroll
            for (int j2 = 0; j2 < 4; ++j2) wv[j2] = Wt[tx * 4 + j2][kk];
            #pragma unroll
            for (int i2 = 0; i2 < 4; ++i2)
                #pragma unroll
                for (int j2 = 0; j2 < 4; ++j2)
                    acc[i2][j2] += av[i2] * wv[j2];
        }
    }
    #pragma unroll
    for (int i2 = 0; i2 < 4; ++i2) {
        int m = m0 + ty * 4 + i2;
        #pragma unroll
        for (int j2 = 0; j2 < 4; ++j2) {
            int n = n0 + tx * 4 + j2;
            float v = acc[i2][j2];
            if (b1) v += b1[n];
            C[(size_t)m * N + n] = v;
        }
    }
}

// ---------------- persistent sequential LSTM ----------------
// 16 blocks; block x owns hidden units [x*32, x*32+32). Wave w computes gate w
// via MFMA with Whh fragments in NAMED VGPRs (forced residency). h exchanged as
// bf16 B-fragments via agent-coherent (sc1) relaxed atomics -> NO per-step L2
// invalidate/writeback; flags via relaxed atomics + in-wave vmcnt drain.
#define LSTM_BLOCKS 16

#define DECLW(i) bf16x8 Wa##i, Wb##i;
#define LOADW(i) { \
    float4 a0 = *(const float4*)(wr0 + (i)*32); \
    float4 a1 = *(const float4*)(wr0 + (i)*32 + 4); \
    float4 c0 = *(const float4*)(wr1 + (i)*32); \
    float4 c1 = *(const float4*)(wr1 + (i)*32 + 4); \
    Wa##i[0]=b16(a0.x); Wa##i[1]=b16(a0.y); Wa##i[2]=b16(a0.z); Wa##i[3]=b16(a0.w); \
    Wa##i[4]=b16(a1.x); Wa##i[5]=b16(a1.y); Wa##i[6]=b16(a1.z); Wa##i[7]=b16(a1.w); \
    Wb##i[0]=b16(c0.x); Wb##i[1]=b16(c0.y); Wb##i[2]=b16(c0.z); Wb##i[3]=b16(c0.w); \
    Wb##i[4]=b16(c1.x); Wb##i[5]=b16(c1.y); Wb##i[6]=b16(c1.z); Wb##i[7]=b16(c1.w); }
#define KSTEP(i) { \
    frag_u fu; \
    fu.u[0] = ald(src + (i)*128); \
    fu.u[1] = ald(src + (i)*128 + 1); \
    acc0 = __builtin_amdgcn_mfma_f32_16x16x32_bf16(Wa##i, fu.v, acc0, 0, 0, 0); \
    acc1 = __builtin_amdgcn_mfma_f32_16x16x32_bf16(Wb##i, fu.v, acc1, 0, 0, 0); }

__launch_bounds__(256, 1)
__global__ void k_lstm(const float* __restrict__ Whh, const float* __restrict__ xg,
                       float* __restrict__ hs, unsigned long long* __restrict__ bfr,
                       int* __restrict__ flags)
{
    __shared__ float gl[4][32][9];          // [gate][unit][batch] (+pad)
    __shared__ unsigned short hsh[32][8];   // h bf16 bits for fragment packing
    const int tid  = threadIdx.x;
    const int lane = tid & 63;
    const int w    = tid >> 6;       // wave = gate index 0..3 (i,f,g,o)
    const int x    = blockIdx.x;
    const int m_l  = lane & 15;      // MFMA row within tile
    const int kg   = lane >> 4;      // k-group (8 elems)
    const int n    = lane & 15;      // MFMA col = batch (valid < 8)

    // ---- Whh rows -> named VGPR bf16 A-fragments (once) ----
    const float* wr0 = Whh + (size_t)(w * 512 + x * 32 + m_l) * 512 + kg * 8;
    const float* wr1 = wr0 + (size_t)16 * 512;
    DECLW(0)  DECLW(1)  DECLW(2)  DECLW(3)  DECLW(4)  DECLW(5)  DECLW(6)  DECLW(7)
    DECLW(8)  DECLW(9)  DECLW(10) DECLW(11) DECLW(12) DECLW(13) DECLW(14) DECLW(15)
    LOADW(0)  LOADW(1)  LOADW(2)  LOADW(3)  LOADW(4)  LOADW(5)  LOADW(6)  LOADW(7)
    LOADW(8)  LOADW(9)  LOADW(10) LOADW(11) LOADW(12) LOADW(13) LOADW(14) LOADW(15)
    asm volatile("" : "+v"(Wa0), "+v"(Wb0), "+v"(Wa1), "+v"(Wb1), "+v"(Wa2), "+v"(Wb2),
                      "+v"(Wa3), "+v"(Wb3), "+v"(Wa4), "+v"(Wb4), "+v"(Wa5), "+v"(Wb5),
                      "+v"(Wa6), "+v"(Wb6), "+v"(Wa7), "+v"(Wb7));
    asm volatile("" : "+v"(Wa8), "+v"(Wb8), "+v"(Wa9), "+v"(Wb9), "+v"(Wa10), "+v"(Wb10),
                      "+v"(Wa11), "+v"(Wb11), "+v"(Wa12), "+v"(Wb12), "+v"(Wa13), "+v"(Wb13),
                      "+v"(Wa14), "+v"(Wb14), "+v"(Wa15), "+v"(Wb15));

    const int u_l = tid >> 3;        // pointwise: unit 0..31
    const int b   = tid & 7;         //            batch 0..7
    float creg = 0.f;

    for (int t = 0; t < L_; ++t) {
        // prefetch xg for this step (independent of h, stays cached in L2 now)
        const float* xr = xg + ((size_t)t * B_ + b) * 2048 + x * 32 + u_l;
        float xi = xr[0], xf = xr[512], xgg = xr[1024], xo = xr[1536];

        f32x4 acc0 = {0.f, 0.f, 0.f, 0.f};
        f32x4 acc1 = {0.f, 0.f, 0.f, 0.f};
        if (t > 0) {
            if (w == 0) {            // wave 0 waits for all blocks' step t-1
                for (;;) {
                    int v = (lane < LSTM_BLOCKS)
                        ? __hip_atomic_load(&flags[lane], __ATOMIC_RELAXED, __HIP_MEMORY_SCOPE_AGENT)
                        : t;
                    if (__all(v >= t)) break;
                    __builtin_amdgcn_s_sleep(1);
                }
            }
            __syncthreads();
            // B-fragments of h_{t-1}: parity (t-1)&1 == (t+1)&1
            const unsigned long long* src =
                bfr + (size_t)((t + 1) & 1) * 2048 + lane * 2;
            KSTEP(0)  KSTEP(1)  KSTEP(2)  KSTEP(3)  KSTEP(4)  KSTEP(5)  KSTEP(6)  KSTEP(7)
            KSTEP(8)  KSTEP(9)  KSTEP(10) KSTEP(11) KSTEP(12) KSTEP(13) KSTEP(14) KSTEP(15)
        } else {
            __syncthreads();
        }
        // D layout: col = lane&15 (batch), row = kg*4 + i (unit within 16-tile)
        if (n < 8) {
            #pragma unroll
            for (int i = 0; i < 4; ++i) {
                gl[w][kg * 4 + i][n]      = acc0[i];
                gl[w][16 + kg * 4 + i][n] = acc1[i];
            }
        }
        __syncthreads();
        // pointwise LSTM cell: thread = (unit u_l, batch b)
        {
            float gi = gl[0][u_l][b] + xi;
            float gf = gl[1][u_l][b] + xf;
            float gg = gl[2][u_l][b] + xgg;
            float go = gl[3][u_l][b] + xo;
            float iv = sigf(gi), fv = sigf(gf), gv = tanhf(gg), ov = sigf(go);
            creg = fv * creg + iv * gv;
            float h = ov * tanhf(creg);
            hs[((size_t)t * B_ + b) * H_ + x * 32 + u_l] = h;
            hsh[u_l][b] = (unsigned short)b16(h);
        }
        __syncthreads();
        // wave 0 packs h into u64 fragment chunks and stores agent-coherent
        if (tid < 64) {
            int bb   = tid & 7;
            int q    = (tid >> 3) & 3;
            int half = (tid >> 5) & 1;
            int u0   = q * 8 + half * 4;
            unsigned long long val =
                  (unsigned long long)hsh[u0 + 0][bb]
                | ((unsigned long long)hsh[u0 + 1][bb] << 16)
                | ((unsigned long long)hsh[u0 + 2][bb] << 32)
                | ((unsigned long long)hsh[u0 + 3][bb] << 48);
            ast(bfr + (size_t)(t & 1) * 2048 + x * 128 + (bb + 16 * q) * 2 + half, val);
        }
        if (tid == 0) {
            asm volatile("s_waitcnt vmcnt(0)" ::: "memory");   // wave 0's frag stores done
            __hip_atomic_store(&flags[x], t + 1, __ATOMIC_RELAXED, __HIP_MEMORY_SCOPE_AGENT);
        }
    }
}

// ---------------- attention + context + gcat(bf16) + st, one block per (t,b) ----------------
__launch_bounds__(256)
__global__ void k_attn(const float* __restrict__ hs, const float* __restrict__ km,
                       const float* __restrict__ q, const float* __restrict__ vw,
                       const float* __restrict__ vb, const int* __restrict__ nt,
                       const int* __restrict__ pt, const float* __restrict__ Wsv,
                       const float* __restrict__ bs, bf16* __restrict__ gcat,
                       float* __restrict__ logattn, float* __restrict__ stbuf)
{
    const int r = blockIdx.x;
    const int t = r >> 3, b = r & 7;
    const int tid = threadIdx.x;
    const int lane = tid & 63, wave = tid >> 6;
    int s = t - A_; if (s < 0) s = 0;
    __shared__ float qv[512];
    __shared__ float vwl[512];
    __shared__ float sc[A_];
    __shared__ float attn[A_];
    __shared__ float red[4];
    for (int i = tid; i < 512; i += 256) { qv[i] = q[(size_t)r * 512 + i]; vwl[i] = vw[i]; }
    __syncthreads();
    for (int a = wave; a < A_; a += 4) {
        int pos = s + a;
        float v = -1e20f;
        bool masked = (pos >= t) || (nt[b * L_ + pos] == VN_ - 1);
        if (!masked) {
            const float* kr = km + (size_t)(pos * B_ + b) * 512;
            float p = 0.f;
            for (int k = lane; k < 512; k += 64)
                p += vwl[k] * tanhf(qv[k] + kr[k]);
            for (int off = 32; off; off >>= 1) p += __shfl_down(p, off);
            v = p + vb[0];
        }
        if (lane == 0) sc[a] = v;
    }
    __syncthreads();
    if (tid < 64) {   // masked softmax over 50 (exact -1e20 semantics; all-masked -> uniform)
        float v = (tid < A_) ? sc[tid] : -INFINITY;
        float m = v;
        for (int off = 32; off; off >>= 1) m = fmaxf(m, __shfl_xor(m, off));
        float e = (tid < A_) ? expf(v - m) : 0.f;
        float d = e;
        for (int off = 32; off; off >>= 1) d += __shfl_xor(d, off);
        if (tid < A_) {
            attn[tid] = e / d;
            logattn[(size_t)r * A_ + tid] = (v - m) - logf(d);
        }
    }
    __syncthreads();
    const int k0 = tid * 2;
    float c0 = 0.f, c1 = 0.f;
    for (int a = 0; a < A_; ++a) {
        int pos = s + a;
        if (pos >= t) break;   // hs rows >= t were zeros at step t (ref semantics)
        float w = attn[a];
        const float2 hv = *(const float2*)(hs + (size_t)(pos * B_ + b) * 512 + k0);
        c0 += w * hv.x; c1 += w * hv.y;
    }
    const float2 hcur = *(const float2*)(hs + (size_t)(t * B_ + b) * 512 + k0);
    int par = (t == 0) ? 0 : pt[b * L_ + t - 1];
    float2 hpar = make_float2(0.f, 0.f);
    if (par < t) hpar = *(const float2*)(hs + (size_t)(par * B_ + b) * 512 + k0);
    bf16* g = gcat + (size_t)r * 1536;
    g[k0]            = __float2bfloat16(c0);
    g[k0 + 1]        = __float2bfloat16(c1);
    g[512 + k0]      = __float2bfloat16(hcur.x);
    g[512 + k0 + 1]  = __float2bfloat16(hcur.y);
    g[1024 + k0]     = __float2bfloat16(hpar.x);
    g[1024 + k0 + 1] = __float2bfloat16(hpar.y);
    float part = c0 * Wsv[k0] + c1 * Wsv[k0 + 1]
               + hcur.x * Wsv[512 + k0] + hcur.y * Wsv[512 + k0 + 1];
    for (int off = 32; off; off >>= 1) part += __shfl_down(part, off);
    if (lane == 0) red[wave] = part;
    __syncthreads();
    if (tid == 0) {
        float z = red[0] + red[1] + red[2] + red[3] + bs[0];
        stbuf[r] = -log1pf(expf(-z));   // log_sigmoid(z)
    }
}

// ---------------- bf16 MFMA GEMM: C[M][N] = A[M][K] x B (+b1+b2) ----------------
// BT=1: B stored [N][K] (transposed weights). BT=0: B stored [K][N].
template<int BT>
__launch_bounds__(256)
__global__ void k_mfma_t(const bf16* __restrict__ Ag, const bf16* __restrict__ Bg,
                         const float* __restrict__ b1, const float* __restrict__ b2,
                         float* __restrict__ C, int N, int K)
{
    __shared__ short Al[64][40];   // [m][k] 32k + pad
    __shared__ short Bl[64][40];   // [n][k] + pad
    const int m0 = blockIdx.y * 64, n0 = blockIdx.x * 64;
    const int tid = threadIdx.x;
    const int lane = tid & 63, wave = tid >> 6;
    f32x4 acc[4] = {};
    for (int k0 = 0; k0 < K; k0 += 32) {
        __syncthreads();
        {
            int r = tid >> 2, c = (tid & 3) * 8;
            bf16x8 v = *(const bf16x8*)(Ag + (size_t)(m0 + r) * K + k0 + c);
            *(bf16x8*)&Al[r][c] = v;
        }
        if (BT) {
            int r = tid >> 2, c = (tid & 3) * 8;
            bf16x8 v = *(const bf16x8*)(Bg + (size_t)(n0 + r) * K + k0 + c);
            *(bf16x8*)&Bl[r][c] = v;
        } else {
            int kr = tid >> 3, cn = (tid & 7) * 8;
            bf16x8 v = *(const bf16x8*)(Bg + (size_t)(k0 + kr) * NGP_ + n0 + cn);
            #pragma unroll
            for (int e = 0; e < 8; ++e) Bl[cn + e][kr] = v[e];
        }
        __syncthreads();
        const int row = lane & 15, kg = (lane >> 4) * 8;
        bf16x8 a = *(const bf16x8*)&Al[wave * 16 + row][kg];
        #pragma unroll
        for (int f = 0; f < 4; ++f) {
            bf16x8 bv = *(const bf16x8*)&Bl[f * 16 + row][kg];
            acc[f] = __builtin_amdgcn_mfma_f32_16x16x32_bf16(a, bv, acc[f], 0, 0, 0);
        }
    }
    const int col = lane & 15, rq = (lane >> 4) * 4;
    #pragma unroll
    for (int f = 0; f < 4; ++f)
        #pragma unroll
        for (int i = 0; i < 4; ++i) {
            int nn = n0 + f * 16 + col;
            float v = acc[f][i];
            if (b1) v += b1[nn];
            if (b2) v += b2[nn];
            C[(size_t)(m0 + wave * 16 + rq + i) * N + nn] = v;
        }
}

// ---------------- per-row logsumexp / loss / argmax-pred ----------------
__launch_bounds__(256)
__global__ void k_loss(const float* __restrict__ logits, const float* __restrict__ bg,
                       const float* __restrict__ logattn, const float* __restrict__ stbuf,
                       const int* __restrict__ tt, float* __restrict__ out)
{
    const int r = blockIdx.x;
    const int t = r >> 3, b = r & 7;
    const int tid = threadIdx.x;
    const int lane = tid & 63, wave = tid >> 6;
    const float* row = logits + (size_t)r * NGP_;
    float vmax = -INFINITY; int vidx = 0;
    for (int n = tid; n < NG_; n += 256) {
        float v = row[n] + bg[n];
        if (v > vmax) { vmax = v; vidx = n; }   // strict > keeps first index per thread
    }
    __shared__ float smax[4]; __shared__ int sidx[4]; __shared__ float ssum[4];
    for (int off = 32; off; off >>= 1) {
        float om = __shfl_down(vmax, off); int oi = __shfl_down(vidx, off);
        if (om > vmax || (om == vmax && oi < vidx)) { vmax = om; vidx = oi; }
    }
    if (lane == 0) { smax[wave] = vmax; sidx[wave] = vidx; }
    __syncthreads();
    if (tid == 0) {
        for (int w = 1; w < 4; ++w)
            if (smax[w] > vmax || (smax[w] == vmax && sidx[w] < vidx)) { vmax = smax[w]; vidx = sidx[w]; }
        smax[0] = vmax; sidx[0] = vidx;
    }
    __syncthreads();
    vmax = smax[0];
    const int amax1 = sidx[0];
    float se = 0.f;
    for (int n = tid; n < NG_; n += 256) se += expf(row[n] + bg[n] - vmax);
    for (int off = 32; off; off >>= 1) se += __shfl_down(se, off);
    if (lane == 0) ssum[wave] = se;
    __syncthreads();
    if (tid == 0) {
        float d = ssum[0] + ssum[1] + ssum[2] + ssum[3];
        float lse = vmax + logf(d);
        float st = stbuf[r];
        const float* la = logattn + (size_t)r * A_;
        float lamax = la[0]; int aidx = 0;
        for (int a = 1; a < A_; ++a) if (la[a] > lamax) { lamax = la[a]; aidx = a; }
        float e1 = -expm1f(st);
        e1 = fminf(fmaxf(e1, 1e-18f), 1e18f);
        float lm = logf(e1);
        float p1 = st + vmax - lse;
        float p2 = lm + lamax;
        int pred = (p1 >= p2) ? amax1 : (NG_ + aidx);   // tie -> earlier (part1) index
        int tgt = tt[b * L_ + t];
        float loss = -(st + (row[tgt] + bg[tgt]) - lse);
        atomicAdd(&out[0], loss);
        out[1 + b * L_ + t] = (float)pred;
    }
}

extern "C" void kernel_launch(void* const* d_in, const int* in_sizes, int n_in,
                              void* d_out, int out_size, void* d_ws, size_t ws_size,
                              hipStream_t stream)
{
    (void)in_sizes; (void)n_in; (void)out_size; (void)ws_size;
    const int*   nt    = (const int*)d_in[0];
    const int*   tt    = (const int*)d_in[1];
    const int*   pt    = (const int*)d_in[2];
    const float* embN  = (const float*)d_in[3];
    const float* embT  = (const float*)d_in[4];
    const float* W_hid = (const float*)d_in[5];
    const float* b_hid = (const float*)d_in[6];
    const float* W_mem = (const float*)d_in[7];
    const float* b_mem = (const float*)d_in[8];
    const float* v_w   = (const float*)d_in[9];
    const float* v_b   = (const float*)d_in[10];
    const float* W_ih  = (const float*)d_in[11];
    const float* W_hh  = (const float*)d_in[12];
    const float* b_ih  = (const float*)d_in[13];
    const float* b_hh  = (const float*)d_in[14];
    const float* W_g   = (const float*)d_in[15];
    const float* b_g   = (const float*)d_in[16];
    const float* W_s   = (const float*)d_in[17];
    const float* b_s   = (const float*)d_in[18];
    float* out = (float*)d_out;

    char* ws = (char*)d_ws;
    size_t o = 0;
    bf16*  WGB  = (bf16*)(ws + o);  o += (size_t)1536 * NGP_ * 2;   // 30.9 MB
    float* LOG  = (float*)(ws + o); o += (size_t)R_ * NGP_ * 4;     // 41.2 MB
    float* XG   = (float*)(ws + o); o += (size_t)R_ * 2048 * 4;     // 8.4 MB
    float* HS   = (float*)(ws + o); o += (size_t)R_ * H_ * 4;       // 2 MB
    float* KM   = (float*)(ws + o); o += (size_t)R_ * H_ * 4;
    float* QB   = (float*)(ws + o); o += (size_t)R_ * H_ * 4;
    bf16*  XB   = (bf16*)(ws + o);  o += (size_t)R_ * H_ * 2;       // 1 MB
    bf16*  WIHB = (bf16*)(ws + o);  o += (size_t)2048 * 512 * 2;    // 2 MB
    bf16*  GC   = (bf16*)(ws + o);  o += (size_t)R_ * 1536 * 2;     // 3.1 MB
    float* LA   = (float*)(ws + o); o += (size_t)R_ * A_ * 4;
    float* ST   = (float*)(ws + o); o += (size_t)R_ * 4;
    unsigned long long* BFR = (unsigned long long*)(ws + o); o += (size_t)4096 * 8; // 32 KB
    int*   FLG  = (int*)(ws + o);   o += 256;

    k_init<<<1, 256, 0, stream>>>(FLG, out);
    k_wgconv<<<2048, 256, 0, stream>>>(W_g, WGB);
    k_w2b<<<1024, 256, 0, stream>>>(W_ih, WIHB, 2048 * 512);
    k_embed<<<R_ * H_ / 256, 256, 0, stream>>>(nt, tt, embN, embT, XB);
    k_mfma_t<1><<<dim3(2048 / 64, R_ / 64), 256, 0, stream>>>(XB, WIHB, b_ih, b_hh, XG, 2048, 512);
    k_lstm<<<LSTM_BLOCKS, 256, 0, stream>>>(W_hh, XG, HS, BFR, FLG);
    k_gemm_at<<<dim3(512 / 64, R_ / 64), 256, 0, stream>>>(HS, W_mem, b_mem, KM, 512, 512);
    k_gemm_at<<<dim3(512 / 64, R_ / 64), 256, 0, stream>>>(HS, W_hid, b_hid, QB, 512, 512);
    k_attn<<<R_, 256, 0, stream>>>(HS, KM, QB, v_w, v_b, nt, pt, W_s, b_s, GC, LA, ST);
    k_mfma_t<0><<<dim3(NGP_ / 64, R_ / 64), 256, 0, stream>>>(GC, WGB, nullptr, nullptr, LOG, NGP_, 1536);
    k_loss<<<R_, 256, 0, stream>>>(LOG, b_g, LA, ST, tt, out);
}

// Round 5
// 741.651 us; speedup vs baseline: 3.1420x; 1.3054x over previous
//
#include <hip/hip_runtime.h>
#include <hip/hip_bf16.h>
#include <math.h>

#define H_ 512
#define VN_ 1000
#define NG_ 10003   // VT+3
#define NGP_ 10112  // padded N for 128-tiles (79*128)
#define A_ 50
#define B_ 8
#define L_ 128
#define R_ 1024     // L*B

typedef __hip_bfloat16 bf16;
typedef __attribute__((ext_vector_type(8))) short bf16x8;
typedef __attribute__((ext_vector_type(4))) float f32x4;

typedef union { unsigned long long u[2]; bf16x8 v; } frag_u;

__device__ __forceinline__ float sigf(float x) { return 1.0f / (1.0f + expf(-x)); }

__device__ __forceinline__ short b16(float v) {
    __hip_bfloat16 h = __float2bfloat16(v);
    return *(short*)&h;
}

__device__ __forceinline__ unsigned long long ald(const unsigned long long* p) {
    return __hip_atomic_load(p, __ATOMIC_RELAXED, __HIP_MEMORY_SCOPE_AGENT);
}
__device__ __forceinline__ void ast32(unsigned int* p, unsigned int v) {
    __hip_atomic_store(p, v, __ATOMIC_RELAXED, __HIP_MEMORY_SCOPE_AGENT);
}

// ---------------- init: flags + loss accumulator ----------------
__global__ void k_init(int* flags, float* out)
{
    if (threadIdx.x < 32)
        __hip_atomic_store(&flags[threadIdx.x], 0, __ATOMIC_RELAXED, __HIP_MEMORY_SCOPE_AGENT);
    if (threadIdx.x == 0) out[0] = 0.f;
}

// ---------------- W_g transpose: f32 [1536][10003] -> bf16 [10112][1536] ----------------
__global__ void k_wgt(const float* __restrict__ Wg, bf16* __restrict__ WT)
{
    __shared__ short S[64][65];
    const int tid = threadIdx.x;
    const int n0 = blockIdx.x * 64, k0 = blockIdx.y * 64;
    const int c = tid & 63;          // n offset (coalesced read)
    const int r0 = (tid >> 6) * 16;  // k base
    #pragma unroll
    for (int i = 0; i < 16; ++i) {
        int k = r0 + i;
        int n = n0 + c;
        float v = (n < NG_) ? Wg[(size_t)(k0 + k) * NG_ + n] : 0.f;
        S[c][k] = b16(v);
    }
    __syncthreads();
    const int n_l = tid >> 2;
    const int kq = (tid & 3) * 16;
    bf16* dst = WT + (size_t)(n0 + n_l) * 1536 + k0 + kq;
    #pragma unroll
    for (int j = 0; j < 2; ++j) {
        bf16x8 v;
        #pragma unroll
        for (int e = 0; e < 8; ++e) v[e] = S[n_l][kq + j * 8 + e];
        *(bf16x8*)(dst + j * 8) = v;
    }
}

// ---------------- flat f32 -> bf16 convert (W_ih) ----------------
__global__ void k_w2b(const float* __restrict__ src, bf16* __restrict__ dst, int n)
{
    for (int i = blockIdx.x * blockDim.x + threadIdx.x; i < n; i += gridDim.x * blockDim.x)
        dst[i] = __float2bfloat16(src[i]);
}

// ---------------- embedding concat -> bf16 ----------------
__global__ void k_embed(const int* __restrict__ nt, const int* __restrict__ tt,
                        const float* __restrict__ embN, const float* __restrict__ embT,
                        bf16* __restrict__ X)
{
    int i = blockIdx.x * blockDim.x + threadIdx.x;   // < 1024*512
    int r = i >> 9, k = i & 511;
    int t = r >> 3, b = r & 7;
    float v;
    if (k < 256) {
        int id = (t == 0) ? 0 : nt[b * L_ + t - 1];
        v = embN[id * 256 + k];
    } else {
        int id = (t == 0) ? 0 : tt[b * L_ + t - 1];
        v = embT[id * 256 + (k - 256)];
    }
    X[i] = __float2bfloat16(v);
}

// ---------------- generic fp32 GEMM: C[M][N] = A[M][K] * W[N][K]^T (+b1) ----------------
__launch_bounds__(256)
__global__ void k_gemm_at(const float* __restrict__ A, const float* __restrict__ W,
                          const float* __restrict__ b1,
                          float* __restrict__ C, int N, int K)
{
    __shared__ float As[64][17];
    __shared__ float Wt[64][17];
    const int m0 = blockIdx.y * 64;
    const int n0 = blockIdx.x * 64;
    const int tid = threadIdx.x;
    const int ty = tid >> 4, tx = tid & 15;
    float acc[4][4] = {};
    for (int k0 = 0; k0 < K; k0 += 16) {
        __syncthreads();
        for (int i = tid; i < 64 * 16; i += 256) {
            int r = i >> 4, c = i & 15;
            As[r][c] = A[(size_t)(m0 + r) * K + k0 + c];
            Wt[r][c] = W[(size_t)(n0 + r) * K + k0 + c];
        }
        __syncthreads();
        #pragma unroll
        for (int kk = 0; kk < 16; ++kk) {
            float av[4], wv[4];
            #pragma unroll
            for (int i2 = 0; i2 < 4; ++i2) av[i2] = As[ty * 4 + i2][kk];
            #pragma unroll
            for (int j2 = 0; j2 < 4; ++j2) wv[j2] = Wt[tx * 4 + j2][kk];
            #pragma unroll
            for (int i2 = 0; i2 < 4; ++i2)
                #pragma unroll
                for (int j2 = 0; j2 < 4; ++j2)
                    acc[i2][j2] += av[i2] * wv[j2];
        }
    }
    #pragma unroll
    for (int i2 = 0; i2 < 4; ++i2) {
        int m = m0 + ty * 4 + i2;
        #pragma unroll
        for (int j2 = 0; j2 < 4; ++j2) {
            int n = n0 + tx * 4 + j2;
            float v = acc[i2][j2];
            if (b1) v += b1[n];
            C[(size_t)m * N + n] = v;
        }
    }
}

// ---------------- persistent sequential LSTM ----------------
#define LSTM_BLOCKS 16

#define DECLW(i) bf16x8 Wa##i, Wb##i;
#define LOADW(i) { \
    float4 a0 = *(const float4*)(wr0 + (i)*32); \
    float4 a1 = *(const float4*)(wr0 + (i)*32 + 4); \
    float4 c0 = *(const float4*)(wr1 + (i)*32); \
    float4 c1 = *(const float4*)(wr1 + (i)*32 + 4); \
    Wa##i[0]=b16(a0.x); Wa##i[1]=b16(a0.y); Wa##i[2]=b16(a0.z); Wa##i[3]=b16(a0.w); \
    Wa##i[4]=b16(a1.x); Wa##i[5]=b16(a1.y); Wa##i[6]=b16(a1.z); Wa##i[7]=b16(a1.w); \
    Wb##i[0]=b16(c0.x); Wb##i[1]=b16(c0.y); Wb##i[2]=b16(c0.z); Wb##i[3]=b16(c0.w); \
    Wb##i[4]=b16(c1.x); Wb##i[5]=b16(c1.y); Wb##i[6]=b16(c1.z); Wb##i[7]=b16(c1.w); }
#define LDF(i) frag_u fu##i; fu##i.u[0] = ald(src + (i)*128); fu##i.u[1] = ald(src + (i)*128 + 1);
#define MM(i) \
    acc0 = __builtin_amdgcn_mfma_f32_16x16x32_bf16(Wa##i, fu##i.v, acc0, 0, 0, 0); \
    acc1 = __builtin_amdgcn_mfma_f32_16x16x32_bf16(Wb##i, fu##i.v, acc1, 0, 0, 0);

__launch_bounds__(256, 1)
__global__ void k_lstm(const float* __restrict__ Whh, const float* __restrict__ xg,
                       float* __restrict__ hs, unsigned long long* __restrict__ bfr,
                       int* __restrict__ flags)
{
    __shared__ float gl[4][32][9];          // [gate][unit][batch] (+pad)
    const int tid  = threadIdx.x;
    const int lane = tid & 63;
    const int w    = tid >> 6;       // wave = gate index 0..3 (i,f,g,o)
    const int x    = blockIdx.x;
    const int m_l  = lane & 15;      // MFMA row within tile
    const int kg   = lane >> 4;      // k-group
    const int n    = lane & 15;      // MFMA col = batch (valid < 8)
    unsigned int* bfr32 = (unsigned int*)bfr;

    // ---- Whh rows -> VGPR/AGPR bf16 A-fragments (once) ----
    const float* wr0 = Whh + (size_t)(w * 512 + x * 32 + m_l) * 512 + kg * 8;
    const float* wr1 = wr0 + (size_t)16 * 512;
    DECLW(0)  DECLW(1)  DECLW(2)  DECLW(3)  DECLW(4)  DECLW(5)  DECLW(6)  DECLW(7)
    DECLW(8)  DECLW(9)  DECLW(10) DECLW(11) DECLW(12) DECLW(13) DECLW(14) DECLW(15)
    LOADW(0)  LOADW(1)  LOADW(2)  LOADW(3)  LOADW(4)  LOADW(5)  LOADW(6)  LOADW(7)
    LOADW(8)  LOADW(9)  LOADW(10) LOADW(11) LOADW(12) LOADW(13) LOADW(14) LOADW(15)
    asm volatile("" : "+v"(Wa0), "+v"(Wb0), "+v"(Wa1), "+v"(Wb1), "+v"(Wa2), "+v"(Wb2),
                      "+v"(Wa3), "+v"(Wb3), "+v"(Wa4), "+v"(Wb4), "+v"(Wa5), "+v"(Wb5),
                      "+v"(Wa6), "+v"(Wb6), "+v"(Wa7), "+v"(Wb7));
    asm volatile("" : "+v"(Wa8), "+v"(Wb8), "+v"(Wa9), "+v"(Wb9), "+v"(Wa10), "+v"(Wb10),
                      "+v"(Wa11), "+v"(Wb11), "+v"(Wa12), "+v"(Wb12), "+v"(Wa13), "+v"(Wb13),
                      "+v"(Wa14), "+v"(Wb14), "+v"(Wa15), "+v"(Wb15));

    const int u_l = tid >> 3;        // pointwise: unit 0..31
    const int b   = tid & 7;         //            batch 0..7
    float creg = 0.f;

    for (int t = 0; t < L_; ++t) {
        // prefetch xg for this step (independent of h)
        const float* xr = xg + ((size_t)t * B_ + b) * 2048 + x * 32 + u_l;
        float xi = xr[0], xf = xr[512], xgg = xr[1024], xo = xr[1536];

        f32x4 acc0 = {0.f, 0.f, 0.f, 0.f};
        f32x4 acc1 = {0.f, 0.f, 0.f, 0.f};
        if (t > 0) {
            // ALL waves poll flags (no barrier needed before loads)
            for (;;) {
                int v = (lane < LSTM_BLOCKS)
                    ? __hip_atomic_load(&flags[lane], __ATOMIC_RELAXED, __HIP_MEMORY_SCOPE_AGENT)
                    : t;
                if (__all(v >= t)) break;
                __builtin_amdgcn_s_sleep(1);
            }
            // batched fragment loads: issue all 32, ONE wait, then MFMAs
            const unsigned long long* src =
                bfr + (size_t)((t + 1) & 1) * 2048 + lane * 2;
            LDF(0)  LDF(1)  LDF(2)  LDF(3)  LDF(4)  LDF(5)  LDF(6)  LDF(7)
            LDF(8)  LDF(9)  LDF(10) LDF(11) LDF(12) LDF(13) LDF(14) LDF(15)
            __builtin_amdgcn_sched_barrier(0);
            MM(0)  MM(1)  MM(2)  MM(3)  MM(4)  MM(5)  MM(6)  MM(7)
            MM(8)  MM(9)  MM(10) MM(11) MM(12) MM(13) MM(14) MM(15)
        }
        // D layout: col = lane&15 (batch), row = kg*4 + i (unit within 16-tile)
        if (n < 8) {
            #pragma unroll
            for (int i = 0; i < 4; ++i) {
                gl[w][kg * 4 + i][n]      = acc0[i];
                gl[w][16 + kg * 4 + i][n] = acc1[i];
            }
        }
        __syncthreads();
        // pointwise LSTM cell: thread = (unit u_l, batch b)
        {
            float gi = gl[0][u_l][b] + xi;
            float gf = gl[1][u_l][b] + xf;
            float gg = gl[2][u_l][b] + xgg;
            float go = gl[3][u_l][b] + xo;
            float iv = sigf(gi), fv = sigf(gf), gv = tanhf(gg), ov = sigf(go);
            creg = fv * creg + iv * gv;
            float h = ov * tanhf(creg);
            hs[((size_t)t * B_ + b) * H_ + x * 32 + u_l] = h;
            // pack unit pair via shfl (partner = tid^8, same wave), store u32 frag
            float h2 = __shfl_xor(h, 8);
            if ((u_l & 1) == 0) {
                unsigned int val = (unsigned int)(unsigned short)b16(h)
                                 | ((unsigned int)(unsigned short)b16(h2) << 16);
                int q = u_l >> 3, p = (u_l & 7) >> 1;
                ast32(bfr32 + (size_t)(t & 1) * 4096 + x * 256 + (b + 16 * q) * 4 + p, val);
            }
        }
        asm volatile("s_waitcnt vmcnt(0)" ::: "memory");  // own stores drained
        __syncthreads();                                  // all threads' stores drained
        if (tid == 0)
            __hip_atomic_store(&flags[x], t + 1, __ATOMIC_RELAXED, __HIP_MEMORY_SCOPE_AGENT);
    }
}

// ---------------- attention + context + gcat(bf16) + st, one block per (t,b) ----------------
__launch_bounds__(256)
__global__ void k_attn(const float* __restrict__ hs, const float* __restrict__ km,
                       const float* __restrict__ q, const float* __restrict__ vw,
                       const float* __restrict__ vb, const int* __restrict__ nt,
                       const int* __restrict__ pt, const float* __restrict__ Wsv,
                       const float* __restrict__ bs, bf16* __restrict__ gcat,
                       float* __restrict__ logattn, float* __restrict__ stbuf)
{
    const int r = blockIdx.x;
    const int t = r >> 3, b = r & 7;
    const int tid = threadIdx.x;
    const int lane = tid & 63, wave = tid >> 6;
    int s = t - A_; if (s < 0) s = 0;
    __shared__ float qv[512];
    __shared__ float vwl[512];
    __shared__ float sc[A_];
    __shared__ float attn[A_];
    __shared__ float red[4];
    for (int i = tid; i < 512; i += 256) { qv[i] = q[(size_t)r * 512 + i]; vwl[i] = vw[i]; }
    __syncthreads();
    for (int a = wave; a < A_; a += 4) {
        int pos = s + a;
        float v = -1e20f;
        bool masked = (pos >= t) || (nt[b * L_ + pos] == VN_ - 1);
        if (!masked) {
            const float* kr = km + (size_t)(pos * B_ + b) * 512;
            float p = 0.f;
            for (int k = lane; k < 512; k += 64)
                p += vwl[k] * tanhf(qv[k] + kr[k]);
            for (int off = 32; off; off >>= 1) p += __shfl_down(p, off);
            v = p + vb[0];
        }
        if (lane == 0) sc[a] = v;
    }
    __syncthreads();
    if (tid < 64) {   // masked softmax over 50 (exact -1e20 semantics; all-masked -> uniform)
        float v = (tid < A_) ? sc[tid] : -INFINITY;
        float m = v;
        for (int off = 32; off; off >>= 1) m = fmaxf(m, __shfl_xor(m, off));
        float e = (tid < A_) ? expf(v - m) : 0.f;
        float d = e;
        for (int off = 32; off; off >>= 1) d += __shfl_xor(d, off);
        if (tid < A_) {
            attn[tid] = e / d;
            logattn[(size_t)r * A_ + tid] = (v - m) - logf(d);
        }
    }
    __syncthreads();
    const int k0 = tid * 2;
    float c0 = 0.f, c1 = 0.f;
    for (int a = 0; a < A_; ++a) {
        int pos = s + a;
        if (pos >= t) break;   // hs rows >= t were zeros at step t (ref semantics)
        float w = attn[a];
        const float2 hv = *(const float2*)(hs + (size_t)(pos * B_ + b) * 512 + k0);
        c0 += w * hv.x; c1 += w * hv.y;
    }
    const float2 hcur = *(const float2*)(hs + (size_t)(t * B_ + b) * 512 + k0);
    int par = (t == 0) ? 0 : pt[b * L_ + t - 1];
    float2 hpar = make_float2(0.f, 0.f);
    if (par < t) hpar = *(const float2*)(hs + (size_t)(par * B_ + b) * 512 + k0);
    bf16* g = gcat + (size_t)r * 1536;
    g[k0]            = __float2bfloat16(c0);
    g[k0 + 1]        = __float2bfloat16(c1);
    g[512 + k0]      = __float2bfloat16(hcur.x);
    g[512 + k0 + 1]  = __float2bfloat16(hcur.y);
    g[1024 + k0]     = __float2bfloat16(hpar.x);
    g[1024 + k0 + 1] = __float2bfloat16(hpar.y);
    float part = c0 * Wsv[k0] + c1 * Wsv[k0 + 1]
               + hcur.x * Wsv[512 + k0] + hcur.y * Wsv[512 + k0 + 1];
    for (int off = 32; off; off >>= 1) part += __shfl_down(part, off);
    if (lane == 0) red[wave] = part;
    __syncthreads();
    if (tid == 0) {
        float z = red[0] + red[1] + red[2] + red[3] + bs[0];
        stbuf[r] = -log1pf(expf(-z));   // log_sigmoid(z)
    }
}

// ---------------- bf16 MFMA GEMM (64-tile, B transposed [N][K]): XG path ----------------
__launch_bounds__(256)
__global__ void k_mfma_bt(const bf16* __restrict__ Ag, const bf16* __restrict__ Bg,
                          const float* __restrict__ b1, const float* __restrict__ b2,
                          float* __restrict__ C, int N, int K)
{
    __shared__ short Al[64][40];
    __shared__ short Bl[64][40];
    const int m0 = blockIdx.y * 64, n0 = blockIdx.x * 64;
    const int tid = threadIdx.x;
    const int lane = tid & 63, wave = tid >> 6;
    f32x4 acc[4] = {};
    for (int k0 = 0; k0 < K; k0 += 32) {
        __syncthreads();
        {
            int r = tid >> 2, c = (tid & 3) * 8;
            *(bf16x8*)&Al[r][c] = *(const bf16x8*)(Ag + (size_t)(m0 + r) * K + k0 + c);
            *(bf16x8*)&Bl[r][c] = *(const bf16x8*)(Bg + (size_t)(n0 + r) * K + k0 + c);
        }
        __syncthreads();
        const int row = lane & 15, kg = (lane >> 4) * 8;
        bf16x8 a = *(const bf16x8*)&Al[wave * 16 + row][kg];
        #pragma unroll
        for (int f = 0; f < 4; ++f) {
            bf16x8 bv = *(const bf16x8*)&Bl[f * 16 + row][kg];
            acc[f] = __builtin_amdgcn_mfma_f32_16x16x32_bf16(a, bv, acc[f], 0, 0, 0);
        }
    }
    const int col = lane & 15, rq = (lane >> 4) * 4;
    #pragma unroll
    for (int f = 0; f < 4; ++f)
        #pragma unroll
        for (int i = 0; i < 4; ++i) {
            int nn = n0 + f * 16 + col;
            float v = acc[f][i];
            if (b1) v += b1[nn];
            if (b2) v += b2[nn];
            C[(size_t)(m0 + wave * 16 + rq + i) * N + nn] = v;
        }
}

// ---------------- 128x128 MFMA GEMM with global_load_lds: logits ----------------
// C[M][N] = A[M][K] x BT[N][K]^T. K%32==0, M%128==0, N%128==0.
__launch_bounds__(256, 2)
__global__ void k_gemm128(const bf16* __restrict__ Ag, const bf16* __restrict__ Bg,
                          float* __restrict__ C, int N, int K)
{
    __shared__ short As[128 * 32];   // [row][32k], chunk-swizzled
    __shared__ short Bs[128 * 32];
    const int tid = threadIdx.x;
    const int lane = tid & 63, wave = tid >> 6;
    const int wr = wave >> 1, wc = wave & 1;
    const int m0 = blockIdx.y * 128, n0 = blockIdx.x * 128;
    f32x4 acc[4][4] = {};
    for (int k0 = 0; k0 < K; k0 += 32) {
        __syncthreads();
        #pragma unroll
        for (int h = 0; h < 2; ++h) {
            int o = tid + h * 256;              // chunk id 0..511 (16B each)
            int row = o >> 2;
            int kc = (o & 3) ^ (row & 3);       // pre-swizzled source chunk
            const bf16* ga = Ag + (size_t)(m0 + row) * K + k0 + kc * 8;
            const bf16* gb = Bg + (size_t)(n0 + row) * K + k0 + kc * 8;
            unsigned ldso = h * 4096 + wave * 1024;   // wave-uniform base (+lane*16 by HW)
            __builtin_amdgcn_global_load_lds(
                (const __attribute__((address_space(1))) void*)ga,
                (__attribute__((address_space(3))) void*)((char*)As + ldso), 16, 0, 0);
            __builtin_amdgcn_global_load_lds(
                (const __attribute__((address_space(1))) void*)gb,
                (__attribute__((address_space(3))) void*)((char*)Bs + ldso), 16, 0, 0);
        }
        asm volatile("s_waitcnt vmcnt(0)" ::: "memory");
        __syncthreads();
        bf16x8 af[4], bf[4];
        #pragma unroll
        for (int mi = 0; mi < 4; ++mi) {
            int ra = wr * 64 + mi * 16 + (lane & 15);
            af[mi] = *(const bf16x8*)&As[ra * 32 + (((lane >> 4) ^ (ra & 3)) * 8)];
        }
        #pragma unroll
        for (int ni = 0; ni < 4; ++ni) {
            int rb = wc * 64 + ni * 16 + (lane & 15);
            bf[ni] = *(const bf16x8*)&Bs[rb * 32 + (((lane >> 4) ^ (rb & 3)) * 8)];
        }
        #pragma unroll
        for (int mi = 0; mi < 4; ++mi)
            #pragma unroll
            for (int ni = 0; ni < 4; ++ni)
                acc[mi][ni] = __builtin_amdgcn_mfma_f32_16x16x32_bf16(af[mi], bf[ni], acc[mi][ni], 0, 0, 0);
    }
    const int col = lane & 15, rq = (lane >> 4) * 4;
    #pragma unroll
    for (int mi = 0; mi < 4; ++mi)
        #pragma unroll
        for (int ni = 0; ni < 4; ++ni) {
            int nn = n0 + wc * 64 + ni * 16 + col;
            #pragma unroll
            for (int i = 0; i < 4; ++i)
                C[(size_t)(m0 + wr * 64 + mi * 16 + rq + i) * N + nn] = acc[mi][ni][i];
        }
}

// ---------------- per-row logsumexp / loss / argmax-pred ----------------
__launch_bounds__(256)
__global__ void k_loss(const float* __restrict__ logits, const float* __restrict__ bg,
                       const float* __restrict__ logattn, const float* __restrict__ stbuf,
                       const int* __restrict__ tt, float* __restrict__ out)
{
    const int r = blockIdx.x;
    const int t = r >> 3, b = r & 7;
    const int tid = threadIdx.x;
    const int lane = tid & 63, wave = tid >> 6;
    const float* row = logits + (size_t)r * NGP_;
    float vmax = -INFINITY; int vidx = 0;
    for (int n = tid; n < NG_; n += 256) {
        float v = row[n] + bg[n];
        if (v > vmax) { vmax = v; vidx = n; }
    }
    __shared__ float smax[4]; __shared__ int sidx[4]; __shared__ float ssum[4];
    for (int off = 32; off; off >>= 1) {
        float om = __shfl_down(vmax, off); int oi = __shfl_down(vidx, off);
        if (om > vmax || (om == vmax && oi < vidx)) { vmax = om; vidx = oi; }
    }
    if (lane == 0) { smax[wave] = vmax; sidx[wave] = vidx; }
    __syncthreads();
    if (tid == 0) {
        for (int w = 1; w < 4; ++w)
            if (smax[w] > vmax || (smax[w] == vmax && sidx[w] < vidx)) { vmax = smax[w]; vidx = sidx[w]; }
        smax[0] = vmax; sidx[0] = vidx;
    }
    __syncthreads();
    vmax = smax[0];
    const int amax1 = sidx[0];
    float se = 0.f;
    for (int n = tid; n < NG_; n += 256) se += expf(row[n] + bg[n] - vmax);
    for (int off = 32; off; off >>= 1) se += __shfl_down(se, off);
    if (lane == 0) ssum[wave] = se;
    __syncthreads();
    if (tid == 0) {
        float d = ssum[0] + ssum[1] + ssum[2] + ssum[3];
        float lse = vmax + logf(d);
        float st = stbuf[r];
        const float* la = logattn + (size_t)r * A_;
        float lamax = la[0]; int aidx = 0;
        for (int a = 1; a < A_; ++a) if (la[a] > lamax) { lamax = la[a]; aidx = a; }
        float e1 = -expm1f(st);
        e1 = fminf(fmaxf(e1, 1e-18f), 1e18f);
        float lm = logf(e1);
        float p1 = st + vmax - lse;
        float p2 = lm + lamax;
        int pred = (p1 >= p2) ? amax1 : (NG_ + aidx);
        int tgt = tt[b * L_ + t];
        float loss = -(st + (row[tgt] + bg[tgt]) - lse);
        atomicAdd(&out[0], loss);
        out[1 + b * L_ + t] = (float)pred;
    }
}

extern "C" void kernel_launch(void* const* d_in, const int* in_sizes, int n_in,
                              void* d_out, int out_size, void* d_ws, size_t ws_size,
                              hipStream_t stream)
{
    (void)in_sizes; (void)n_in; (void)out_size; (void)ws_size;
    const int*   nt    = (const int*)d_in[0];
    const int*   tt    = (const int*)d_in[1];
    const int*   pt    = (const int*)d_in[2];
    const float* embN  = (const float*)d_in[3];
    const float* embT  = (const float*)d_in[4];
    const float* W_hid = (const float*)d_in[5];
    const float* b_hid = (const float*)d_in[6];
    const float* W_mem = (const float*)d_in[7];
    const float* b_mem = (const float*)d_in[8];
    const float* v_w   = (const float*)d_in[9];
    const float* v_b   = (const float*)d_in[10];
    const float* W_ih  = (const float*)d_in[11];
    const float* W_hh  = (const float*)d_in[12];
    const float* b_ih  = (const float*)d_in[13];
    const float* b_hh  = (const float*)d_in[14];
    const float* W_g   = (const float*)d_in[15];
    const float* b_g   = (const float*)d_in[16];
    const float* W_s   = (const float*)d_in[17];
    const float* b_s   = (const float*)d_in[18];
    float* out = (float*)d_out;

    char* ws = (char*)d_ws;
    size_t o = 0;
    bf16*  WGT  = (bf16*)(ws + o);  o += (size_t)NGP_ * 1536 * 2;   // 31.1 MB, [N][K]
    float* LOG  = (float*)(ws + o); o += (size_t)R_ * NGP_ * 4;     // 41.4 MB
    float* XG   = (float*)(ws + o); o += (size_t)R_ * 2048 * 4;     // 8.4 MB
    float* HS   = (float*)(ws + o); o += (size_t)R_ * H_ * 4;       // 2 MB
    float* KM   = (float*)(ws + o); o += (size_t)R_ * H_ * 4;
    float* QB   = (float*)(ws + o); o += (size_t)R_ * H_ * 4;
    bf16*  XB   = (bf16*)(ws + o);  o += (size_t)R_ * H_ * 2;       // 1 MB
    bf16*  WIHB = (bf16*)(ws + o);  o += (size_t)2048 * 512 * 2;    // 2 MB
    bf16*  GC   = (bf16*)(ws + o);  o += (size_t)R_ * 1536 * 2;     // 3.1 MB
    float* LA   = (float*)(ws + o); o += (size_t)R_ * A_ * 4;
    float* ST   = (float*)(ws + o); o += (size_t)R_ * 4;
    unsigned long long* BFR = (unsigned long long*)(ws + o); o += (size_t)4096 * 8;
    int*   FLG  = (int*)(ws + o);   o += 256;

    k_init<<<1, 256, 0, stream>>>(FLG, out);
    k_wgt<<<dim3(NGP_ / 64, 1536 / 64), 256, 0, stream>>>(W_g, WGT);
    k_w2b<<<1024, 256, 0, stream>>>(W_ih, WIHB, 2048 * 512);
    k_embed<<<R_ * H_ / 256, 256, 0, stream>>>(nt, tt, embN, embT, XB);
    k_mfma_bt<<<dim3(2048 / 64, R_ / 64), 256, 0, stream>>>(XB, WIHB, b_ih, b_hh, XG, 2048, 512);
    k_lstm<<<LSTM_BLOCKS, 256, 0, stream>>>(W_hh, XG, HS, BFR, FLG);
    k_gemm_at<<<dim3(512 / 64, R_ / 64), 256, 0, stream>>>(HS, W_mem, b_mem, KM, 512, 512);
    k_gemm_at<<<dim3(512 / 64, R_ / 64), 256, 0, stream>>>(HS, W_hid, b_hid, QB, 512, 512);
    k_attn<<<R_, 256, 0, stream>>>(HS, KM, QB, v_w, v_b, nt, pt, W_s, b_s, GC, LA, ST);
    k_gemm128<<<dim3(NGP_ / 128, R_ / 128), 256, 0, stream>>>(GC, WGT, LOG, NGP_, 1536);
    k_loss<<<R_, 256, 0, stream>>>(LOG, b_g, LA, ST, tt, out);
}